// Round 3
// baseline (211.743 us; speedup 1.0000x reference)
//
#include <hip/hip_runtime.h>

// ---- ordered-uint encoding for float atomicMax (monotone bijection) ----
__device__ __forceinline__ unsigned ford(float f) {
    unsigned u = __float_as_uint(f);
    return (u & 0x80000000u) ? ~u : (u | 0x80000000u);
}
__device__ __forceinline__ float funord(unsigned u) {
    return (u & 0x80000000u) ? __uint_as_float(u & 0x7fffffffu) : __uint_as_float(~u);
}

// init out=bias, zero smax/den/cnt, and per-node attention projections:
// ps[n] = feat[n]·attn_w[0:32], pd[n] = feat[n]·attn_w[32:64]
__global__ void k_init(float* __restrict__ out, const float* __restrict__ bias,
                       const float* __restrict__ feat, const float* __restrict__ attn_w,
                       float* __restrict__ ps, float* __restrict__ pd,
                       unsigned* __restrict__ smaxu, float* __restrict__ den,
                       int* __restrict__ cnt, int N) {
    int idx = blockIdx.x * blockDim.x + threadIdx.x;
    if (idx < 2) cnt[idx] = 0;
    if (idx < 2 * N) { smaxu[idx] = 0u; den[idx] = 0.f; }
    if (idx < N * 32) out[idx] = bias[idx & 31];
    if (idx < N) {
        const float4* zp = (const float4*)(feat + (long)idx * 32);
        const float4* aw = (const float4*)attn_w;
        float a = 0.f, b = 0.f;
        #pragma unroll
        for (int j = 0; j < 8; ++j) {
            float4 z = zp[j], wa = aw[j], wb = aw[8 + j];
            a = fmaf(z.x, wa.x, a); a = fmaf(z.y, wa.y, a);
            a = fmaf(z.z, wa.z, a); a = fmaf(z.w, wa.w, a);
            b = fmaf(z.x, wb.x, b); b = fmaf(z.y, wb.y, b);
            b = fmaf(z.z, wb.z, b); b = fmaf(z.w, wb.w, b);
        }
        ps[idx] = a; pd[idx] = b;
    }
}

__global__ void k_score(const int* __restrict__ src, const int* __restrict__ dst,
                        const int* __restrict__ etype,
                        const float* __restrict__ ps, const float* __restrict__ pd,
                        const float* __restrict__ attn_b,
                        float* __restrict__ score, unsigned* __restrict__ smaxu,
                        int E, int N) {
    int e = blockIdx.x * blockDim.x + threadIdx.x;
    if (e >= E) return;
    float sc = ps[src[e]] + pd[dst[e]] + attn_b[0];
    sc = sc >= 0.f ? sc : 0.01f * sc;  // leaky_relu
    score[e] = sc;
    atomicMax(&smaxu[etype[e] * N + dst[e]], ford(sc));
}

// exp + denominator atomics, fused with relation partition (ballot + atomic append).
__global__ void k_mid(const int* __restrict__ dst, const int* __restrict__ etype,
                      const float* __restrict__ score, const unsigned* __restrict__ smaxu,
                      float* __restrict__ ex, float* __restrict__ den,
                      int* __restrict__ perm0, int* __restrict__ perm1,
                      int* __restrict__ cnt, int E, int N) {
    int e = blockIdx.x * blockDim.x + threadIdx.x;
    bool valid = e < E;
    int d = 0, r = 0;
    if (valid) {
        d = dst[e]; r = etype[e];
        float m = funord(smaxu[r * N + d]);
        float v = expf(score[e] - m);
        ex[e] = v;
        atomicAdd(&den[r * N + d], v);
    }
    unsigned long long b1 = __ballot(valid && (r == 1));
    unsigned long long b0 = __ballot(valid && (r == 0));
    int lane = threadIdx.x & 63;
    int base0 = 0, base1 = 0;
    if (lane == 0) {
        if (b0) base0 = atomicAdd(&cnt[0], (int)__popcll(b0));
        if (b1) base1 = atomicAdd(&cnt[1], (int)__popcll(b1));
    }
    base0 = __shfl(base0, 0);
    base1 = __shfl(base1, 0);
    unsigned long long lt = (1ull << lane) - 1ull;
    if (valid) {
        if (r) perm1[base1 + (int)__popcll(b1 & lt)] = e;
        else   perm0[base0 + (int)__popcll(b0 & lt)] = e;
    }
}

// Message + scatter. Block = 256 threads: 8 o-lanes x 32 edge-slots, 4 edges/thread
// -> 128 edges/block. Variant v=bid&3: r=v>>1, f-half=v&1 (f-split doubles waves;
// bid&3 pins variant per XCD-residue for L1 W locality). ic-outer/f-inner with
// depth-3 rotating W prefetch window.
__global__ __launch_bounds__(256) void k_msg(
    const float* __restrict__ feat, const float* __restrict__ efeat,
    const int* __restrict__ src, const int* __restrict__ dst,
    const float* __restrict__ w1p, const float* __restrict__ b1p,
    const float* __restrict__ w2p, const float* __restrict__ b2p,
    const float* __restrict__ ex, const float* __restrict__ den,
    const int* __restrict__ perm0, const int* __restrict__ perm1,
    const int* __restrict__ cnt, float* __restrict__ out, int N) {
    int v = blockIdx.x & 3;
    int chunk = blockIdx.x >> 2;
    int r = v >> 1, h = v & 1;
    int count = cnt[r];
    int base = chunk * 128;
    if (base >= count) return;
    const int*   perm = r ? perm1 : perm0;
    const float* W    = r ? w2p : w1p;
    const float* B    = r ? b2p : b1p;
    const int f0 = h ? 9 : 0;
    const int nf = h ? 8 : 9;   // h0: f=0..8 (9 rows); h1: f=9..16 (8 rows, 16=bias)

    __shared__ float z_lds[128][36];
    __shared__ float u_lds[128][20];

    {   // stage z (32 f) and u (16 f, col16=1.0 for bias row) for 128 edges
        int row = threadIdx.x >> 1, half = threadIdx.x & 1;
        int gi = base + row;
        int e = perm[min(gi, count - 1)];
        int s = src[e];
        const float4* zp = (const float4*)(feat + (long)s * 32 + half * 16);
        float4 a0 = zp[0], a1 = zp[1], a2 = zp[2], a3 = zp[3];
        const float4* up = (const float4*)(efeat + (long)e * 16 + half * 8);
        float4 c0 = up[0], c1 = up[1];
        float* zd = &z_lds[row][half * 16];
        *(float4*)(zd + 0) = a0; *(float4*)(zd + 4) = a1;
        *(float4*)(zd + 8) = a2; *(float4*)(zd + 12) = a3;
        float* ud = &u_lds[row][half * 8];
        *(float4*)(ud + 0) = c0; *(float4*)(ud + 4) = c1;
        if (half) ud[8] = 1.f;   // u_lds[row][16] = 1.0 (bias row multiplier)
    }
    __syncthreads();

    int slot = threadIdx.x >> 3, ol = threadIdx.x & 7;
    int li[4], dj[4]; float al[4];
    #pragma unroll
    for (int j = 0; j < 4; ++j) {
        li[j] = j * 32 + slot;
        int gi = base + li[j];
        bool vv = gi < count;
        int e = perm[min(gi, count - 1)];
        dj[j] = dst[e];
        al[j] = vv ? ex[e] / den[r * N + dj[j]] : 0.f;
    }

    float msg[4][4];
    #pragma unroll
    for (int j = 0; j < 4; ++j) { msg[j][0]=0; msg[j][1]=0; msg[j][2]=0; msg[j][3]=0; }

    float4 wv[3][4];
    for (int ic = 0; ic < 8; ++ic) {
        const int icoff = ic * 128 + ol * 4;
        float4 z0 = *(const float4*)&z_lds[li[0]][ic * 4];
        float4 z1 = *(const float4*)&z_lds[li[1]][ic * 4];
        float4 z2 = *(const float4*)&z_lds[li[2]][ic * 4];
        float4 z3 = *(const float4*)&z_lds[li[3]][ic * 4];
        #pragma unroll
        for (int w = 0; w < 3; ++w) {   // prologue: f0+0..f0+2 (nf>=8 so all valid)
            int f = f0 + w;
            const float* rb = ((f < 16) ? (W + f * 1024) : B) + icoff;
            wv[w][0] = *(const float4*)(rb);
            wv[w][1] = *(const float4*)(rb + 32);
            wv[w][2] = *(const float4*)(rb + 64);
            wv[w][3] = *(const float4*)(rb + 96);
        }
        #pragma unroll
        for (int fi = 0; fi < 9; ++fi) {
            if (fi < nf) {
                int f = f0 + fi;
                // copy window slot to locals, then issue prefetch, then compute
                float4 a0 = wv[fi % 3][0], a1 = wv[fi % 3][1];
                float4 a2 = wv[fi % 3][2], a3 = wv[fi % 3][3];
                int fn = fi + 3;
                if (fn < nf) {
                    int f2 = f0 + fn;
                    const float* rb = ((f2 < 16) ? (W + f2 * 1024) : B) + icoff;
                    wv[fi % 3][0] = *(const float4*)(rb);
                    wv[fi % 3][1] = *(const float4*)(rb + 32);
                    wv[fi % 3][2] = *(const float4*)(rb + 64);
                    wv[fi % 3][3] = *(const float4*)(rb + 96);
                }
                float u0 = u_lds[li[0]][f], u1 = u_lds[li[1]][f];
                float u2 = u_lds[li[2]][f], u3 = u_lds[li[3]][f];
                #define ACC(WV, CX) \
                { float p0 = u0 * z0.CX, p1 = u1 * z1.CX, p2 = u2 * z2.CX, p3 = u3 * z3.CX; \
                  msg[0][0] = fmaf(p0, WV.x, msg[0][0]); msg[0][1] = fmaf(p0, WV.y, msg[0][1]); \
                  msg[0][2] = fmaf(p0, WV.z, msg[0][2]); msg[0][3] = fmaf(p0, WV.w, msg[0][3]); \
                  msg[1][0] = fmaf(p1, WV.x, msg[1][0]); msg[1][1] = fmaf(p1, WV.y, msg[1][1]); \
                  msg[1][2] = fmaf(p1, WV.z, msg[1][2]); msg[1][3] = fmaf(p1, WV.w, msg[1][3]); \
                  msg[2][0] = fmaf(p2, WV.x, msg[2][0]); msg[2][1] = fmaf(p2, WV.y, msg[2][1]); \
                  msg[2][2] = fmaf(p2, WV.z, msg[2][2]); msg[2][3] = fmaf(p2, WV.w, msg[2][3]); \
                  msg[3][0] = fmaf(p3, WV.x, msg[3][0]); msg[3][1] = fmaf(p3, WV.y, msg[3][1]); \
                  msg[3][2] = fmaf(p3, WV.z, msg[3][2]); msg[3][3] = fmaf(p3, WV.w, msg[3][3]); }
                ACC(a0, x) ACC(a1, y) ACC(a2, z) ACC(a3, w)
                #undef ACC
            }
        }
    }

    #pragma unroll
    for (int j = 0; j < 4; ++j) {
        float a = al[j];
        float* op = out + (long)dj[j] * 32 + ol * 4;
        atomicAdd(op + 0, a * msg[j][0]);
        atomicAdd(op + 1, a * msg[j][1]);
        atomicAdd(op + 2, a * msg[j][2]);
        atomicAdd(op + 3, a * msg[j][3]);
    }
}

extern "C" void kernel_launch(void* const* d_in, const int* in_sizes, int n_in,
                              void* d_out, int out_size, void* d_ws, size_t ws_size,
                              hipStream_t stream) {
    const float* feat   = (const float*)d_in[0];
    const float* efeat  = (const float*)d_in[1];
    const int*   src    = (const int*)d_in[2];
    const int*   dst    = (const int*)d_in[3];
    const int*   etype  = (const int*)d_in[4];
    const float* attn_w = (const float*)d_in[5];
    const float* attn_b = (const float*)d_in[6];
    const float* ef1_w  = (const float*)d_in[7];
    const float* ef1_b  = (const float*)d_in[8];
    const float* ef2_w  = (const float*)d_in[9];
    const float* ef2_b  = (const float*)d_in[10];
    const float* bias   = (const float*)d_in[11];

    int E = in_sizes[2];
    int N = in_sizes[0] / 32;

    float*    score = (float*)d_ws;
    float*    ex    = score + E;
    unsigned* smaxu = (unsigned*)(ex + E);
    float*    den   = (float*)(smaxu + 2 * N);
    int*      cnt   = (int*)(den + 2 * N);
    int*      perm0 = cnt + 2;
    int*      perm1 = perm0 + E;
    float*    ps    = (float*)(perm1 + E);
    float*    pd    = ps + N;
    float*    out   = (float*)d_out;

    int initTotal = N * 32;
    k_init<<<(initTotal + 255) / 256, 256, 0, stream>>>(out, bias, feat, attn_w,
                                                        ps, pd, smaxu, den, cnt, N);
    k_score<<<(E + 255) / 256, 256, 0, stream>>>(src, dst, etype, ps, pd, attn_b,
                                                 score, smaxu, E, N);
    k_mid<<<(E + 255) / 256, 256, 0, stream>>>(dst, etype, score, smaxu, ex, den,
                                               perm0, perm1, cnt, E, N);
    int nch = (E + 127) / 128;
    k_msg<<<4 * nch, 256, 0, stream>>>(feat, efeat, src, dst,
                                       ef1_w, ef1_b, ef2_w, ef2_b,
                                       ex, den, perm0, perm1, cnt, out, N);
}

// Round 4
// 157.004 us; speedup vs baseline: 1.3486x; 1.3486x over previous
//
#include <hip/hip_runtime.h>

typedef __attribute__((ext_vector_type(8))) short bf16x8;
typedef __attribute__((ext_vector_type(16))) float f32x16;

// f32 -> bf16 (round-to-nearest-even)
__device__ __forceinline__ unsigned short f2b(float x) {
    unsigned u = __float_as_uint(x);
    unsigned r = (u + 0x7fffu + ((u >> 16) & 1u)) >> 16;
    return (unsigned short)r;
}

// out = bias broadcast; den/cnt zeroed; per-node attention projections
// ps[n] = feat[n]·attn_w[0:32], pd[n] = feat[n]·attn_w[32:64]
__global__ void k_init(float* __restrict__ out, const float* __restrict__ bias,
                       const float* __restrict__ feat, const float* __restrict__ attn_w,
                       float* __restrict__ ps, float* __restrict__ pd,
                       float* __restrict__ den, int* __restrict__ cnt, int N) {
    int idx = blockIdx.x * blockDim.x + threadIdx.x;
    if (idx < 2) cnt[idx] = 0;
    if (idx < 2 * N) den[idx] = 0.f;
    if (idx < N * 32) out[idx] = bias[idx & 31];
    if (idx < N) {
        const float4* zp = (const float4*)(feat + (long)idx * 32);
        const float4* aw = (const float4*)attn_w;
        float a = 0.f, b = 0.f;
        #pragma unroll
        for (int j = 0; j < 8; ++j) {
            float4 z = zp[j], wa = aw[j], wb = aw[8 + j];
            a = fmaf(z.x, wa.x, a); a = fmaf(z.y, wa.y, a);
            a = fmaf(z.z, wa.z, a); a = fmaf(z.w, wa.w, a);
            b = fmaf(z.x, wb.x, b); b = fmaf(z.y, wb.y, b);
            b = fmaf(z.z, wb.z, b); b = fmaf(z.w, wb.w, b);
        }
        ps[idx] = a; pd[idx] = b;
    }
}

// Prepack A-fragments (W'^T tiles) for v_mfma_f32_32x32x16_bf16.
// A tile t rows m=o (cols t*32+o of W'), A[m,kk] with kk = h*16 + (l>>5)*8 + j.
// W'[i, t*32+o] = W[t*1024 + i*32 + o] for t<16; bias tile t=16: B[i*32+o].
// PA frag index: ((r*17 + t)*2 + h)*64 + lane, 8 bf16 each.
__global__ void k_prepack(const float* __restrict__ w1, const float* __restrict__ b1,
                          const float* __restrict__ w2, const float* __restrict__ b2,
                          unsigned short* __restrict__ PA) {
    int gid = blockIdx.x * 256 + threadIdx.x;
    if (gid >= 2 * 17 * 2 * 64) return;
    int l = gid & 63;
    int x = gid >> 6;
    int h = x & 1; x >>= 1;
    int t = x % 17;
    int r = x / 17;
    const float* W = r ? w2 : w1;
    const float* B = r ? b2 : b1;
    int o = l & 31;
    int kb = h * 16 + (l >> 5) * 8;
    unsigned short v[8];
    #pragma unroll
    for (int j = 0; j < 8; ++j) {
        int i = kb + j;
        float s = (t < 16) ? W[t * 1024 + i * 32 + o] : B[i * 32 + o];
        v[j] = f2b(s);
    }
    uint4 pack;
    pack.x = (unsigned)v[0] | ((unsigned)v[1] << 16);
    pack.y = (unsigned)v[2] | ((unsigned)v[3] << 16);
    pack.z = (unsigned)v[4] | ((unsigned)v[5] << 16);
    pack.w = (unsigned)v[6] | ((unsigned)v[7] << 16);
    *((uint4*)PA + gid) = pack;
}

// Fused: score (leaky_relu), exp WITHOUT max-subtraction (scores bounded, f32-safe;
// mathematically identical softmax), denominator atomics, relation partition.
__global__ void k_score2(const int* __restrict__ src, const int* __restrict__ dst,
                         const int* __restrict__ etype,
                         const float* __restrict__ ps, const float* __restrict__ pd,
                         const float* __restrict__ attn_b,
                         float* __restrict__ ex, float* __restrict__ den,
                         int* __restrict__ perm0, int* __restrict__ perm1,
                         int* __restrict__ cnt, int E, int N) {
    int e = blockIdx.x * blockDim.x + threadIdx.x;
    bool valid = e < E;
    int r = 0;
    if (valid) {
        int d = dst[e]; r = etype[e];
        float sc = ps[src[e]] + pd[d] + attn_b[0];
        sc = sc >= 0.f ? sc : 0.01f * sc;   // leaky_relu
        float v = __expf(sc);
        ex[e] = v;
        atomicAdd(&den[r * N + d], v);
    }
    unsigned long long b1 = __ballot(valid && (r == 1));
    unsigned long long b0 = __ballot(valid && (r == 0));
    int lane = threadIdx.x & 63;
    int base0 = 0, base1 = 0;
    if (lane == 0) {
        if (b0) base0 = atomicAdd(&cnt[0], (int)__popcll(b0));
        if (b1) base1 = atomicAdd(&cnt[1], (int)__popcll(b1));
    }
    base0 = __shfl(base0, 0);
    base1 = __shfl(base1, 0);
    unsigned long long lt = (1ull << lane) - 1ull;
    if (valid) {
        if (r) perm1[base1 + (int)__popcll(b1 & lt)] = e;
        else   perm0[base0 + (int)__popcll(b0 & lt)] = e;
    }
}

// MFMA message kernel. Block = 256 thr = 4 waves; 128 edges/block, 32 edges/wave.
// Per wave: B frags = z(bf16) k-halves from LDS; 17 tiles (16 W-rows + bias):
// C = A_t·B (2 chained 32x32x16 MFMA), fold msg += u[edge][t]*C (bias: msg=C).
// C layout (HW-verified): col=lane&31=edge, row o=(reg&3)+8*(reg>>2)+4*(lane>>5).
__global__ __launch_bounds__(256) void k_msg(
    const float* __restrict__ feat, const float* __restrict__ efeat,
    const int* __restrict__ src, const int* __restrict__ dst,
    const unsigned short* __restrict__ PA,
    const float* __restrict__ ex, const float* __restrict__ den,
    const int* __restrict__ perm0, const int* __restrict__ perm1,
    const int* __restrict__ cnt, float* __restrict__ out, int N) {
    int r = blockIdx.y;
    int count = cnt[r];
    int base = blockIdx.x * 128;
    if (count <= 0 || base >= count) return;
    const int* perm = r ? perm1 : perm0;

    __shared__ __align__(16) unsigned short z_bf[128][32];  // 8 KB
    __shared__ float ut[16][128];                           // 8 KB (efeat transposed)
    __shared__ float alph[128];
    __shared__ int dstl[128];

    int tid = threadIdx.x;
    {
        int el = tid >> 1, half = tid & 1;
        int gi = base + el;
        int e = perm[min(gi, count - 1)];
        int s = src[e];
        const float4* zp = (const float4*)(feat + (long)s * 32 + half * 16);
        float4 a0 = zp[0], a1 = zp[1], a2 = zp[2], a3 = zp[3];
        unsigned short* zd = &z_bf[el][half * 16];
        zd[0] = f2b(a0.x); zd[1] = f2b(a0.y); zd[2]  = f2b(a0.z); zd[3]  = f2b(a0.w);
        zd[4] = f2b(a1.x); zd[5] = f2b(a1.y); zd[6]  = f2b(a1.z); zd[7]  = f2b(a1.w);
        zd[8] = f2b(a2.x); zd[9] = f2b(a2.y); zd[10] = f2b(a2.z); zd[11] = f2b(a2.w);
        zd[12] = f2b(a3.x); zd[13] = f2b(a3.y); zd[14] = f2b(a3.z); zd[15] = f2b(a3.w);
        const float4* up = (const float4*)(efeat + (long)e * 16 + half * 8);
        float4 c0 = up[0], c1 = up[1];
        int fb = half * 8;
        ut[fb + 0][el] = c0.x; ut[fb + 1][el] = c0.y;
        ut[fb + 2][el] = c0.z; ut[fb + 3][el] = c0.w;
        ut[fb + 4][el] = c1.x; ut[fb + 5][el] = c1.y;
        ut[fb + 6][el] = c1.z; ut[fb + 7][el] = c1.w;
    }
    if (tid < 128) {
        int gi = base + tid;
        bool vv = gi < count;
        int e = perm[min(gi, count - 1)];
        int d = dst[e];
        dstl[tid] = d;
        alph[tid] = vv ? ex[e] / den[r * N + d] : 0.f;  // den>0 whenever vv
    }
    __syncthreads();

    int lane = tid & 63;
    int ecol = (tid >> 6) * 32 + (lane & 31);    // this lane's edge slot (0..127)
    int kb = (lane >> 5) * 8;
    bf16x8 b0 = *(const bf16x8*)&z_bf[ecol][kb];        // kk 0..15
    bf16x8 b1 = *(const bf16x8*)&z_bf[ecol][16 + kb];   // kk 16..31

    const bf16x8* pa = (const bf16x8*)PA + (long)r * 34 * 64 + lane;

    f32x16 msg;
    {   // bias tile (t=16) first: msg = C
        bf16x8 a0 = pa[32 * 64];
        bf16x8 a1 = pa[33 * 64];
        f32x16 c;
        #pragma unroll
        for (int k = 0; k < 16; ++k) c[k] = 0.f;
        c = __builtin_amdgcn_mfma_f32_32x32x16_bf16(a0, b0, c, 0, 0, 0);
        c = __builtin_amdgcn_mfma_f32_32x32x16_bf16(a1, b1, c, 0, 0, 0);
        msg = c;
    }
    #pragma unroll 4
    for (int t = 0; t < 16; ++t) {
        bf16x8 a0 = pa[(t * 2 + 0) * 64];
        bf16x8 a1 = pa[(t * 2 + 1) * 64];
        f32x16 c;
        #pragma unroll
        for (int k = 0; k < 16; ++k) c[k] = 0.f;
        c = __builtin_amdgcn_mfma_f32_32x32x16_bf16(a0, b0, c, 0, 0, 0);
        c = __builtin_amdgcn_mfma_f32_32x32x16_bf16(a1, b1, c, 0, 0, 0);
        float u = ut[t][ecol];   // lanes 0..31 consecutive, hi-half broadcast
        #pragma unroll
        for (int k = 0; k < 16; ++k) msg[k] = fmaf(u, c[k], msg[k]);
    }

    float al = alph[ecol];
    int dd = dstl[ecol];
    float* op = out + (long)dd * 32 + 4 * (lane >> 5);
    #pragma unroll
    for (int k = 0; k < 16; ++k)
        atomicAdd(op + (k & 3) + 8 * (k >> 2), al * msg[k]);
}

extern "C" void kernel_launch(void* const* d_in, const int* in_sizes, int n_in,
                              void* d_out, int out_size, void* d_ws, size_t ws_size,
                              hipStream_t stream) {
    const float* feat   = (const float*)d_in[0];
    const float* efeat  = (const float*)d_in[1];
    const int*   src    = (const int*)d_in[2];
    const int*   dst    = (const int*)d_in[3];
    const int*   etype  = (const int*)d_in[4];
    const float* attn_w = (const float*)d_in[5];
    const float* attn_b = (const float*)d_in[6];
    const float* ef1_w  = (const float*)d_in[7];
    const float* ef1_b  = (const float*)d_in[8];
    const float* ef2_w  = (const float*)d_in[9];
    const float* ef2_b  = (const float*)d_in[10];
    const float* bias   = (const float*)d_in[11];

    int E = in_sizes[2];
    int N = in_sizes[0] / 32;

    // ws layout (16B-aligned sections): ex E | den 2N | perm0 E | perm1 E | ps N | pd N | PA | cnt
    float*          ex    = (float*)d_ws;
    float*          den   = ex + E;
    int*            perm0 = (int*)(den + 2 * N);
    int*            perm1 = perm0 + E;
    float*          ps    = (float*)(perm1 + E);
    float*          pd    = ps + N;
    unsigned short* PA    = (unsigned short*)(pd + N);          // 2*17*2*64*8 bf16
    int*            cnt   = (int*)(PA + 2 * 17 * 2 * 64 * 8);
    float*          out   = (float*)d_out;

    int initTotal = N * 32;
    k_init<<<(initTotal + 255) / 256, 256, 0, stream>>>(out, bias, feat, attn_w,
                                                        ps, pd, den, cnt, N);
    k_prepack<<<17, 256, 0, stream>>>(ef1_w, ef1_b, ef2_w, ef2_b, PA);
    k_score2<<<(E + 255) / 256, 256, 0, stream>>>(src, dst, etype, ps, pd, attn_b,
                                                  ex, den, perm0, perm1, cnt, E, N);
    dim3 mgrid((E + 127) / 128, 2);
    k_msg<<<mgrid, 256, 0, stream>>>(feat, efeat, src, dst, PA,
                                     ex, den, perm0, perm1, cnt, out, N);
}

// Round 5
// 54.314 us; speedup vs baseline: 3.8985x; 2.8907x over previous
//
#include <hip/hip_runtime.h>

typedef __attribute__((ext_vector_type(8))) short bf16x8;
typedef __attribute__((ext_vector_type(16))) float f32x16;

// f32 -> bf16 (round-to-nearest-even)
__device__ __forceinline__ unsigned short f2b(float x) {
    unsigned u = __float_as_uint(x);
    unsigned r = (u + 0x7fffu + ((u >> 16) & 1u)) >> 16;
    return (unsigned short)r;
}

// Fused init: per-node attention projections ps/pd; MFMA A-fragment prepack;
// histogram of key=r*N+dst (hist pre-zeroed by hipMemsetAsync).
__global__ void k_init(const float* __restrict__ feat, const float* __restrict__ attn_w,
                       const int* __restrict__ dst, const int* __restrict__ etype,
                       const float* __restrict__ w1, const float* __restrict__ b1,
                       const float* __restrict__ w2, const float* __restrict__ b2,
                       float* __restrict__ ps, float* __restrict__ pd,
                       unsigned short* __restrict__ PA, int* __restrict__ hist,
                       int E, int N) {
    int idx = blockIdx.x * blockDim.x + threadIdx.x;
    if (idx < N) {
        const float4* zp = (const float4*)(feat + (long)idx * 32);
        const float4* aw = (const float4*)attn_w;
        float a = 0.f, b = 0.f;
        #pragma unroll
        for (int j = 0; j < 8; ++j) {
            float4 z = zp[j], wa = aw[j], wb = aw[8 + j];
            a = fmaf(z.x, wa.x, a); a = fmaf(z.y, wa.y, a);
            a = fmaf(z.z, wa.z, a); a = fmaf(z.w, wa.w, a);
            b = fmaf(z.x, wb.x, b); b = fmaf(z.y, wb.y, b);
            b = fmaf(z.z, wb.z, b); b = fmaf(z.w, wb.w, b);
        }
        ps[idx] = a; pd[idx] = b;
    }
    if (idx < 2 * 17 * 2 * 64) {   // prepack A-fragments for 32x32x16 bf16
        int l = idx & 63;
        int x = idx >> 6;
        int h = x & 1; x >>= 1;
        int t = x % 17;
        int r = x / 17;
        const float* W = r ? w2 : w1;
        const float* B = r ? b2 : b1;
        int o = l & 31;
        int kb = h * 16 + (l >> 5) * 8;
        unsigned short v[8];
        #pragma unroll
        for (int j = 0; j < 8; ++j) {
            int i = kb + j;
            float s = (t < 16) ? W[t * 1024 + i * 32 + o] : B[i * 32 + o];
            v[j] = f2b(s);
        }
        uint4 pack;
        pack.x = (unsigned)v[0] | ((unsigned)v[1] << 16);
        pack.y = (unsigned)v[2] | ((unsigned)v[3] << 16);
        pack.z = (unsigned)v[4] | ((unsigned)v[5] << 16);
        pack.w = (unsigned)v[6] | ((unsigned)v[7] << 16);
        *((uint4*)PA + idx) = pack;
    }
    if (idx < E) atomicAdd(&hist[etype[idx] * N + dst[idx]], 1);
}

// scan1: block-local exclusive scan of hist (1024 bins/block) -> rowptr, block sums.
__global__ __launch_bounds__(256) void k_scan1(const int* __restrict__ hist,
                                               int* __restrict__ rowptr,
                                               int* __restrict__ bsum, int n) {
    __shared__ int s[256];
    int t = threadIdx.x;
    int i0 = blockIdx.x * 1024 + t * 4;
    int h[4];
    #pragma unroll
    for (int j = 0; j < 4; ++j) h[j] = (i0 + j < n) ? hist[i0 + j] : 0;
    int tot = h[0] + h[1] + h[2] + h[3];
    s[t] = tot;
    __syncthreads();
    for (int d = 1; d < 256; d <<= 1) {
        int x = (t >= d) ? s[t - d] : 0;
        __syncthreads();
        s[t] += x;
        __syncthreads();
    }
    int excl = s[t] - tot;
    int run = excl;
    #pragma unroll
    for (int j = 0; j < 4; ++j) {
        if (i0 + j < n) rowptr[i0 + j] = run;
        run += h[j];
    }
    if (t == 255) bsum[blockIdx.x] = s[255];
}

// scan2: exclusive scan of block sums (single wave, carry loop).
__global__ void k_scan2(int* __restrict__ bsum, int nb) {
    int lane = threadIdx.x & 63;
    int carry = 0;
    for (int c = 0; c < nb; c += 64) {
        int i = c + lane;
        int v = (i < nb) ? bsum[i] : 0;
        int inc = v;
        #pragma unroll
        for (int d = 1; d < 64; d <<= 1) {
            int x = __shfl_up(inc, d);
            if (lane >= d) inc += x;
        }
        if (i < nb) bsum[i] = inc - v + carry;
        carry += __shfl(inc, 63);
    }
}

// scan3: add block offsets; cursor = rowptr; rowptr[n] = E sentinel.
__global__ void k_scan3(int* __restrict__ rowptr, const int* __restrict__ bsum,
                        int* __restrict__ cursor, int n, int E) {
    int i = blockIdx.x * blockDim.x + threadIdx.x;
    if (i < n) {
        int v = rowptr[i] + bsum[i >> 10];
        rowptr[i] = v;
        cursor[i] = v;
    }
    if (i == 0) rowptr[n] = E;
}

// score + exp (no max-subtraction: scores bounded, softmax identical) + sorted scatter.
__global__ void k_score(const int* __restrict__ src, const int* __restrict__ dst,
                        const int* __restrict__ etype,
                        const float* __restrict__ ps, const float* __restrict__ pd,
                        const float* __restrict__ attn_b,
                        int* __restrict__ cursor, int* __restrict__ sortidx,
                        float* __restrict__ exs, int E, int N) {
    int e = blockIdx.x * blockDim.x + threadIdx.x;
    if (e >= E) return;
    int d = dst[e];
    float sc = ps[src[e]] + pd[d] + attn_b[0];
    sc = sc >= 0.f ? sc : 0.01f * sc;   // leaky_relu
    float v = __expf(sc);
    int key = etype[e] * N + d;
    int pos = atomicAdd(&cursor[key], 1);
    sortidx[pos] = e;
    exs[pos] = v;
}

// MFMA message kernel: 128 sorted edges/block, raw msg rows -> wmsg (coalesced, no atomics).
// C layout (HW-verified): col=lane&31=edge, row o=(reg&3)+8*(reg>>2)+4*(lane>>5).
__global__ __launch_bounds__(256) void k_msg(
    const float* __restrict__ feat, const float* __restrict__ efeat,
    const int* __restrict__ src, const unsigned short* __restrict__ PA,
    const int* __restrict__ sortidx, const int* __restrict__ rowptr,
    float* __restrict__ wmsg, int E, int N) {
    int r = blockIdx.y;
    int cnt0 = rowptr[N];
    int relstart = r ? cnt0 : 0;
    int count = r ? (E - cnt0) : cnt0;
    int base = blockIdx.x * 128;
    if (count <= 0 || base >= count) return;

    __shared__ __align__(16) char smem[18432];
    unsigned short (*z_bf)[32] = (unsigned short(*)[32])smem;   // 8 KB
    float (*ut)[128] = (float(*)[128])(smem + 8192);            // 8 KB
    float (*msgl)[36] = (float(*)[36])smem;                     // 18 KB (aliased)

    int tid = threadIdx.x;
    {
        int el = tid >> 1, half = tid & 1;
        int gi = base + el;
        int e = sortidx[relstart + min(gi, count - 1)];
        int s = src[e];
        const float4* zp = (const float4*)(feat + (long)s * 32 + half * 16);
        float4 a0 = zp[0], a1 = zp[1], a2 = zp[2], a3 = zp[3];
        unsigned short* zd = &z_bf[el][half * 16];
        zd[0] = f2b(a0.x); zd[1] = f2b(a0.y); zd[2]  = f2b(a0.z); zd[3]  = f2b(a0.w);
        zd[4] = f2b(a1.x); zd[5] = f2b(a1.y); zd[6]  = f2b(a1.z); zd[7]  = f2b(a1.w);
        zd[8] = f2b(a2.x); zd[9] = f2b(a2.y); zd[10] = f2b(a2.z); zd[11] = f2b(a2.w);
        zd[12] = f2b(a3.x); zd[13] = f2b(a3.y); zd[14] = f2b(a3.z); zd[15] = f2b(a3.w);
        const float4* up = (const float4*)(efeat + (long)e * 16 + half * 8);
        float4 c0 = up[0], c1 = up[1];
        int fb = half * 8;
        ut[fb + 0][el] = c0.x; ut[fb + 1][el] = c0.y;
        ut[fb + 2][el] = c0.z; ut[fb + 3][el] = c0.w;
        ut[fb + 4][el] = c1.x; ut[fb + 5][el] = c1.y;
        ut[fb + 6][el] = c1.z; ut[fb + 7][el] = c1.w;
    }
    __syncthreads();

    int lane = tid & 63;
    int ecol = (tid >> 6) * 32 + (lane & 31);   // edge slot 0..127
    int kb = (lane >> 5) * 8;
    bf16x8 b0 = *(const bf16x8*)&z_bf[ecol][kb];
    bf16x8 b1 = *(const bf16x8*)&z_bf[ecol][16 + kb];

    const bf16x8* pa = (const bf16x8*)PA + (long)r * 34 * 64 + lane;

    f32x16 msg;
    {   // bias tile (t=16): msg = C
        bf16x8 a0 = pa[32 * 64];
        bf16x8 a1 = pa[33 * 64];
        f32x16 c;
        #pragma unroll
        for (int k = 0; k < 16; ++k) c[k] = 0.f;
        c = __builtin_amdgcn_mfma_f32_32x32x16_bf16(a0, b0, c, 0, 0, 0);
        c = __builtin_amdgcn_mfma_f32_32x32x16_bf16(a1, b1, c, 0, 0, 0);
        msg = c;
    }
    float uu[16];
    #pragma unroll
    for (int t = 0; t < 16; ++t) uu[t] = ut[t][ecol];
    #pragma unroll 4
    for (int t = 0; t < 16; ++t) {
        bf16x8 a0 = pa[(t * 2 + 0) * 64];
        bf16x8 a1 = pa[(t * 2 + 1) * 64];
        f32x16 c;
        #pragma unroll
        for (int k = 0; k < 16; ++k) c[k] = 0.f;
        c = __builtin_amdgcn_mfma_f32_32x32x16_bf16(a0, b0, c, 0, 0, 0);
        c = __builtin_amdgcn_mfma_f32_32x32x16_bf16(a1, b1, c, 0, 0, 0);
        #pragma unroll
        for (int k = 0; k < 16; ++k) msg[k] = fmaf(uu[t], c[k], msg[k]);
    }
    __syncthreads();   // all z_bf/ut reads done; smem re-used as msgl

    {
        int ob = 4 * (lane >> 5);
        #pragma unroll
        for (int k = 0; k < 16; ++k)
            msgl[ecol][ob + (k & 3) + 8 * (k >> 2)] = msg[k];
    }
    __syncthreads();

    {   // coalesced store: [128][32] f32 rows at sorted positions
        float4* wb = (float4*)(wmsg + (long)(relstart + base) * 32);
        #pragma unroll
        for (int j = 0; j < 4; ++j) {
            int flat = j * 256 + tid;        // float4 index, 8 per row
            int row = flat >> 3, col = (flat & 7) * 4;
            if (base + row < count)
                wb[flat] = *(const float4*)&msgl[row][col];
        }
    }
}

// Final gather-reduce: thread = (node, o-quad). out = bias + sum_r (exs/den)*wmsg rows.
__global__ void k_reduce(const int* __restrict__ rowptr, const float* __restrict__ exs,
                         const float* __restrict__ wmsg, const float* __restrict__ bias,
                         float* __restrict__ out, int N) {
    int tid = blockIdx.x * blockDim.x + threadIdx.x;
    if (tid >= N * 8) return;
    int n = tid >> 3, og = tid & 7;
    float4 acc = ((const float4*)bias)[og];
    #pragma unroll 1
    for (int r = 0; r < 2; ++r) {
        int k = r * N + n;
        int s = rowptr[k], e2 = rowptr[k + 1];
        if (s >= e2) continue;
        float den = 0.f;
        #pragma unroll 1
        for (int p = s; p < e2; ++p) den += exs[p];
        float inv = 1.f / den;
        #pragma unroll 1
        for (int p = s; p < e2; ++p) {
            float w = exs[p] * inv;
            float4 m = *(const float4*)(wmsg + (long)p * 32 + og * 4);
            acc.x = fmaf(w, m.x, acc.x); acc.y = fmaf(w, m.y, acc.y);
            acc.z = fmaf(w, m.z, acc.z); acc.w = fmaf(w, m.w, acc.w);
        }
    }
    ((float4*)out)[tid] = acc;
}

extern "C" void kernel_launch(void* const* d_in, const int* in_sizes, int n_in,
                              void* d_out, int out_size, void* d_ws, size_t ws_size,
                              hipStream_t stream) {
    const float* feat   = (const float*)d_in[0];
    const float* efeat  = (const float*)d_in[1];
    const int*   src    = (const int*)d_in[2];
    const int*   dst    = (const int*)d_in[3];
    const int*   etype  = (const int*)d_in[4];
    const float* attn_w = (const float*)d_in[5];
    const float* attn_b = (const float*)d_in[6];
    const float* ef1_w  = (const float*)d_in[7];
    const float* ef1_b  = (const float*)d_in[8];
    const float* ef2_w  = (const float*)d_in[9];
    const float* ef2_b  = (const float*)d_in[10];
    const float* bias   = (const float*)d_in[11];

    int E = in_sizes[2];
    int N = in_sizes[0] / 32;
    int n2 = 2 * N;

    // ws layout
    float*          ps      = (float*)d_ws;                    // N
    float*          pd      = ps + N;                          // N
    unsigned short* PA      = (unsigned short*)(pd + N);       // 34816 bf16
    int*            hist    = (int*)(PA + 2 * 17 * 2 * 64 * 8);// 2N
    int*            rowptr  = hist + n2;                       // 2N+1
    int*            cursor  = rowptr + n2 + 1;                 // 2N
    int*            bsum    = cursor + n2;                     // <=64
    int*            sortidx = bsum + 64;                       // E
    float*          exs     = (float*)(sortidx + E);           // E
    float*          wmsg    = (float*)(((size_t)(exs + E) + 15) & ~(size_t)15); // E*32
    float*          out     = (float*)d_out;

    int nb = (n2 + 1023) / 1024;

    hipMemsetAsync(hist, 0, (size_t)n2 * sizeof(int), stream);
    k_init<<<(E + 255) / 256, 256, 0, stream>>>(feat, attn_w, dst, etype,
                                                ef1_w, ef1_b, ef2_w, ef2_b,
                                                ps, pd, PA, hist, E, N);
    k_scan1<<<nb, 256, 0, stream>>>(hist, rowptr, bsum, n2);
    k_scan2<<<1, 64, 0, stream>>>(bsum, nb);
    k_scan3<<<(n2 + 255) / 256, 256, 0, stream>>>(rowptr, bsum, cursor, n2, E);
    k_score<<<(E + 255) / 256, 256, 0, stream>>>(src, dst, etype, ps, pd, attn_b,
                                                 cursor, sortidx, exs, E, N);
    dim3 mgrid((E + 127) / 128, 2);
    k_msg<<<mgrid, 256, 0, stream>>>(feat, efeat, src, PA, sortidx, rowptr,
                                     wmsg, E, N);
    k_reduce<<<(N * 8 + 255) / 256, 256, 0, stream>>>(rowptr, exs, wmsg, bias, out, N);
}